// Round 7
// baseline (303.961 us; speedup 1.0000x reference)
//
#include <hip/hip_runtime.h>

#define BB 32
#define TT 2000
#define NG 500          // float4 groups per alphas row
#define HH 512
#define LL 256
#define THRESH 0.95f

#define BPB 8           // batches per scan block (4 blocks total)
#define RSTRIDE 2004    // LDS row stride in floats (pad -> disjoint bank quads)

// d_ws layout:
//   int2  rec[BB*LL]  : per-fire {t, bits(dist)}  (rem recomputed as a*sc-dist)
//   int   nfires[BB]
//   float scale[BB]

// ---- per-batch rescale factor (bit-identical to R5/R6 phase 1) ----
__global__ __launch_bounds__(256) void cif_scale_kernel(
    const float* __restrict__ alphas, const int* __restrict__ tlen,
    float* __restrict__ scale_g)
{
    const int b = blockIdx.x;
    const int tid = threadIdx.x;
    __shared__ double red[256];
    const float4* a4 = (const float4*)(alphas + b * TT);
    double s = 0.0;
    for (int g = tid; g < NG; g += 256) {
        float4 v = a4[g];
        s += (double)v.x + (double)v.y + (double)v.z + (double)v.w;
    }
    red[tid] = s;
    __syncthreads();
    for (int off = 128; off > 0; off >>= 1) {
        if (tid < off) red[tid] += red[tid + off];
        __syncthreads();
    }
    if (tid == 0)
        scale_g[b] = (float)tlen[b] / (float)red[0];   // f32 divide, as reference
}

// ---- lockstep scan: lane = batch; per-lane contiguous LDS row, explicit
// float4 register pipeline (batched ds_read_b128, latency hidden). ----
__global__ __launch_bounds__(256) void cif_scan_kernel(
    const float* __restrict__ alphas, const float* __restrict__ scale_g,
    int2* __restrict__ rec, int* __restrict__ nfires)
{
    const int b0 = blockIdx.x * BPB;
    const int tid = threadIdx.x;
    __shared__ float sa[BPB * RSTRIDE];      // scaled alphas, row-contiguous
    __shared__ int2 flist[BPB * LL];         // per-lane fire records
    __shared__ float scs[BPB];

    if (tid < BPB) scs[tid] = scale_g[b0 + tid];
    __syncthreads();

    // ---- stage 8 rows -> LDS, pre-scaled (fl(a*sc): the exact mul the
    // gather recomputes). 32-thread group r stages row r, coalesced. ----
    {
        const int r = tid >> 5;
        const int lane = tid & 31;
        const float sc = scs[r];
        const float4* arow4 = (const float4*)(alphas + (size_t)(b0 + r) * TT);
        float4* srow4 = (float4*)(sa + r * RSTRIDE);
        #pragma unroll
        for (int j = 0; j < NG / 32; ++j) {          // 15 full rounds = 480
            const int g = lane + j * 32;
            float4 v = arow4[g];
            v.x *= sc; v.y *= sc; v.z *= sc; v.w *= sc;
            srow4[g] = v;
        }
        const int g = lane + (NG / 32) * 32;         // tail 480..499
        if (g < NG) {
            float4 v = arow4[g];
            v.x *= sc; v.y *= sc; v.z *= sc; v.w *= sc;
            srow4[g] = v;
        }
    }
    __syncthreads();

    // ---- serial lockstep scan on lanes 0..7 (wave 0). Chain per step:
    // add -> cmp -> cndmask (~12 cyc). One ds_read_b128 per 4 steps,
    // prefetched 4 groups (16 steps) ahead. Fires: exec-masked ds_write_b64
    // to a per-lane list, off the float chain. ----
    int nf = 0;
    if (tid < BPB) {
        const float4* s4 = (const float4*)(sa + tid * RSTRIDE);
        int2* fl = flist + tid * LL;
        float integ = 0.0f;

        float4 rbuf[4];
        #pragma unroll
        for (int i = 0; i < 4; ++i) rbuf[i] = s4[i];

        for (int blk = 0; blk < 125; ++blk) {        // 125 x 4 groups = 2000
            #pragma unroll
            for (int i = 0; i < 4; ++i) {
                const int g = blk * 4 + i;
                const float4 c = rbuf[i];
                if (g + 4 < NG) rbuf[i] = s4[g + 4];
                const float av[4] = {c.x, c.y, c.z, c.w};
                #pragma unroll
                for (int j = 0; j < 4; ++j) {
                    const float a = av[j];
                    const float dist = 1.0f - integ;   // off-chain
                    float ii = integ + a;              // integrate += alpha
                    const bool fire = (ii >= THRESH);
                    const float iim1 = ii - 1.0f;      // off-chain vs cmp
                    ii = fire ? iim1 : ii;             // cndmask
                    if (fire) {
                        if (nf < LL) {
                            int2 r;
                            r.x = g * 4 + j;
                            r.y = __float_as_int(dist);
                            fl[nf] = r;
                        }
                        ++nf;
                    }
                    integ = ii;
                }
            }
        }
    }
    __syncthreads();

    // ---- coalesced flush: fire lists -> global rec. Entries beyond nf are
    // garbage; gather never reads l >= nfires[b]. ----
    {
        int2* rg = rec + b0 * LL;
        const int2* fs = flist;
        #pragma unroll
        for (int j = 0; j < (BPB * LL) / 256; ++j)
            rg[tid + j * 256] = fs[tid + j * 256];
    }
    if (tid < BPB) nfires[b0 + tid] = (nf < LL) ? nf : LL;
}

// ---- gather: unchanged from R5/R6 (validated) ----
__global__ __launch_bounds__(128) void cif_gather_kernel(
    const float* __restrict__ hidden, const float* __restrict__ alphas,
    const float* __restrict__ scale_g, const int2* __restrict__ rec,
    const int* __restrict__ nfires, float* __restrict__ out)
{
    const int l = blockIdx.x;       // token index
    const int b = blockIdx.y;       // batch
    const int tid = threadIdx.x;    // 128 threads x float4 = 512 = HH

    float4 acc = make_float4(0.f, 0.f, 0.f, 0.f);
    const int F = nfires[b];
    if (l < F) {
        const int2 re = rec[b * LL + l];
        const int e = re.x;                        // fire step of this token
        const float dist = __int_as_float(re.y);   // weight of frame e
        const float sc = scale_g[b];
        const float* hb = hidden + (size_t)b * TT * HH + (size_t)tid * 4;
        const float* ab = alphas + b * TT;
        int t0 = 0;
        if (l > 0) {
            const int2 rp = rec[b * LL + l - 1];
            const int sp = rp.x;
            const float dp = __int_as_float(rp.y);
            const float rem = ab[sp] * sc - dp;    // a - cur, bit-exact
            const float4 hv = *(const float4*)(hb + (size_t)sp * HH);
            acc.x = rem * hv.x; acc.y = rem * hv.y;
            acc.z = rem * hv.z; acc.w = rem * hv.w;
            t0 = sp + 1;
        }
        // Ascending t (reference order), depth-2 load pipeline; interior
        // weight = alphas[t]*sc (bit-identical to scan), dist at t==e.
        int t = t0;
        float w0 = (t < e) ? ab[t] * sc : dist;
        float4 h0 = *(const float4*)(hb + (size_t)t * HH);
        if (t < e) {
            float w1 = (t + 1 < e) ? ab[t + 1] * sc : dist;
            float4 h1 = *(const float4*)(hb + (size_t)(t + 1) * HH);
            while (t + 2 <= e) {
                const float w2 = (t + 2 < e) ? ab[t + 2] * sc : dist;
                const float4 h2 = *(const float4*)(hb + (size_t)(t + 2) * HH);
                acc.x += w0 * h0.x; acc.y += w0 * h0.y;
                acc.z += w0 * h0.z; acc.w += w0 * h0.w;
                w0 = w1; h0 = h1; w1 = w2; h1 = h2; ++t;
            }
            acc.x += w0 * h0.x; acc.y += w0 * h0.y;
            acc.z += w0 * h0.z; acc.w += w0 * h0.w;
            w0 = w1; h0 = h1;
        }
        acc.x += w0 * h0.x; acc.y += w0 * h0.y;
        acc.z += w0 * h0.z; acc.w += w0 * h0.w;
    }
    *(float4*)(out + ((size_t)b * LL + l) * HH + (size_t)tid * 4) = acc;
}

extern "C" void kernel_launch(void* const* d_in, const int* in_sizes, int n_in,
                              void* d_out, int out_size, void* d_ws, size_t ws_size,
                              hipStream_t stream) {
    const float* hidden = (const float*)d_in[0];   // [B,T,H] f32
    const float* alphas = (const float*)d_in[1];   // [B,T]   f32
    const int*   tlen   = (const int*)d_in[2];     // [B]     i32
    float* out = (float*)d_out;                    // [B,L,H] f32

    int2*  rec     = (int2*)d_ws;
    int*   nfires  = (int*)(rec + BB * LL);
    float* scale_g = (float*)(nfires + BB);

    cif_scale_kernel<<<BB, 256, 0, stream>>>(alphas, tlen, scale_g);
    cif_scan_kernel<<<4, 256, 0, stream>>>(alphas, scale_g, rec, nfires);
    cif_gather_kernel<<<dim3(LL, BB), 128, 0, stream>>>(hidden, alphas, scale_g,
                                                        rec, nfires, out);
}

// Round 8
// 297.415 us; speedup vs baseline: 1.0220x; 1.0220x over previous
//
#include <hip/hip_runtime.h>

#define BB 32
#define TT 2000
#define TP 2048         // padded steps (48 zero rows; zeros can never fire)
#define NWIN 63         // 32-step windows covering 2016 >= 2000 steps
#define NG 500          // float4 groups per alphas row
#define HH 512
#define LL 256
#define THRESH 0.95f

// d_ws layout:
//   float alphasT[TP*BB] : pre-scaled transposed alphas (fl(a*sc)), zero-padded
//   int2  rec[BB*LL]     : per-fire {t, bits(dist)}
//   int   nfires[BB]
//   float scale[BB]

// ---- per-batch rescale + scaled transpose (sum code bit-identical to R5-R7) ----
__global__ __launch_bounds__(256) void cif_scale_kernel(
    const float* __restrict__ alphas, const int* __restrict__ tlen,
    float* __restrict__ scale_g, float* __restrict__ alphasT)
{
    const int b = blockIdx.x;
    const int tid = threadIdx.x;
    __shared__ double red[256];
    __shared__ float s_sc;
    const float4* a4 = (const float4*)(alphas + b * TT);
    double s = 0.0;
    for (int g = tid; g < NG; g += 256) {
        float4 v = a4[g];
        s += (double)v.x + (double)v.y + (double)v.z + (double)v.w;
    }
    red[tid] = s;
    __syncthreads();
    for (int off = 128; off > 0; off >>= 1) {
        if (tid < off) red[tid] += red[tid + off];
        __syncthreads();
    }
    if (tid == 0) {
        const float sc = (float)tlen[b] / (float)red[0];  // f32 divide, as ref
        scale_g[b] = sc;
        s_sc = sc;
    }
    __syncthreads();
    const float sc = s_sc;
    for (int t = tid; t < TP; t += 256)
        alphasT[t * BB + b] = (t < TT) ? alphas[b * TT + t] * sc : 0.0f;
}

// ---- scan: ONE wave, lane = batch. Serial loop: 1 coalesced global load +
// 6 VALU per step, branchless, outputs only boundary integ + fire mask per
// 32-step window. Fires/dists recovered by parallel bit-exact replay. ----
__global__ __launch_bounds__(256) void cif_scan_kernel(
    const float* __restrict__ alphasT, int2* __restrict__ rec,
    int* __restrict__ nfires)
{
    const int tid = threadIdx.x;
    __shared__ unsigned smask[NWIN * BB];   // fire mask per (window, batch)
    __shared__ float sinteg[NWIN * BB];     // integ AFTER window w
    __shared__ int spre[NWIN * BB];         // exclusive prefix of fire counts

    if (tid < BB) {
        const float* colp = alphasT + tid;  // lane's column (stride BB floats)
        float rb[32];                       // 32-step rolling load pipeline
        #pragma unroll
        for (int j = 0; j < 32; ++j) rb[j] = colp[j * BB];
        float integ = 0.0f;
        for (int w = 0; w < NWIN; ++w) {
            const float* nxt = colp + (size_t)(w + 1) * 32 * BB;
            unsigned mask = 0;
            #pragma unroll
            for (int j = 0; j < 32; ++j) {
                const float a = rb[j];
                rb[j] = nxt[j * BB];          // prefetch 32 steps ahead
                float ii = integ + a;         // integrate += alpha
                const bool fire = (ii >= THRESH);
                const float iim1 = ii - 1.0f; // off-chain vs cmp
                ii = fire ? iim1 : ii;        // cndmask
                mask |= fire ? (1u << j) : 0u;
                integ = ii;
            }
            smask[w * BB + tid] = mask;
            sinteg[w * BB + tid] = integ;     // boundary entering window w+1
        }
    }
    __syncthreads();

    // per-batch prefix of window fire counts + nfires
    if (tid < BB) {
        int run = 0;
        for (int w = 0; w < NWIN; ++w) {
            spre[w * BB + tid] = run;
            run += __popc(smask[w * BB + tid]);
        }
        nfires[tid] = (run < LL) ? run : LL;
    }
    __syncthreads();

    // parallel replay: task (w,b) re-runs its 32 steps from the bit-exact
    // boundary integ with IDENTICAL f32 ops -> identical fires and dists.
    for (int r = 0; r < 8; ++r) {
        const int tau = tid + r * 256;
        if (tau < NWIN * BB) {
            const int w = tau >> 5;
            const int b = tau & 31;
            const unsigned m = smask[w * BB + b];
            if (m) {
                float integ = (w == 0) ? 0.0f : sinteg[(w - 1) * BB + b];
                int tok = spre[w * BB + b];
                const float* col = alphasT + b;
                for (int j = 0; j < 32; ++j) {
                    const float a = col[(size_t)(w * 32 + j) * BB];
                    const float dist = 1.0f - integ;   // from OLD integrate
                    float ii = integ + a;
                    if (ii >= THRESH) {
                        if (tok < LL) {
                            int2 rr;
                            rr.x = w * 32 + j;
                            rr.y = __float_as_int(dist);
                            rec[b * LL + tok] = rr;
                        }
                        ++tok;
                        ii -= 1.0f;
                    }
                    integ = ii;
                }
            }
        }
    }
}

// ---- gather: unchanged from R5-R7 (validated) ----
__global__ __launch_bounds__(128) void cif_gather_kernel(
    const float* __restrict__ hidden, const float* __restrict__ alphas,
    const float* __restrict__ scale_g, const int2* __restrict__ rec,
    const int* __restrict__ nfires, float* __restrict__ out)
{
    const int l = blockIdx.x;       // token index
    const int b = blockIdx.y;       // batch
    const int tid = threadIdx.x;    // 128 threads x float4 = 512 = HH

    float4 acc = make_float4(0.f, 0.f, 0.f, 0.f);
    const int F = nfires[b];
    if (l < F) {
        const int2 re = rec[b * LL + l];
        const int e = re.x;                        // fire step of this token
        const float dist = __int_as_float(re.y);   // weight of frame e
        const float sc = scale_g[b];
        const float* hb = hidden + (size_t)b * TT * HH + (size_t)tid * 4;
        const float* ab = alphas + b * TT;
        int t0 = 0;
        if (l > 0) {
            const int2 rp = rec[b * LL + l - 1];
            const int sp = rp.x;
            const float dp = __int_as_float(rp.y);
            const float rem = ab[sp] * sc - dp;    // a - cur, bit-exact
            const float4 hv = *(const float4*)(hb + (size_t)sp * HH);
            acc.x = rem * hv.x; acc.y = rem * hv.y;
            acc.z = rem * hv.z; acc.w = rem * hv.w;
            t0 = sp + 1;
        }
        int t = t0;
        float w0 = (t < e) ? ab[t] * sc : dist;
        float4 h0 = *(const float4*)(hb + (size_t)t * HH);
        if (t < e) {
            float w1 = (t + 1 < e) ? ab[t + 1] * sc : dist;
            float4 h1 = *(const float4*)(hb + (size_t)(t + 1) * HH);
            while (t + 2 <= e) {
                const float w2 = (t + 2 < e) ? ab[t + 2] * sc : dist;
                const float4 h2 = *(const float4*)(hb + (size_t)(t + 2) * HH);
                acc.x += w0 * h0.x; acc.y += w0 * h0.y;
                acc.z += w0 * h0.z; acc.w += w0 * h0.w;
                w0 = w1; h0 = h1; w1 = w2; h1 = h2; ++t;
            }
            acc.x += w0 * h0.x; acc.y += w0 * h0.y;
            acc.z += w0 * h0.z; acc.w += w0 * h0.w;
            w0 = w1; h0 = h1;
        }
        acc.x += w0 * h0.x; acc.y += w0 * h0.y;
        acc.z += w0 * h0.z; acc.w += w0 * h0.w;
    }
    *(float4*)(out + ((size_t)b * LL + l) * HH + (size_t)tid * 4) = acc;
}

extern "C" void kernel_launch(void* const* d_in, const int* in_sizes, int n_in,
                              void* d_out, int out_size, void* d_ws, size_t ws_size,
                              hipStream_t stream) {
    const float* hidden = (const float*)d_in[0];   // [B,T,H] f32
    const float* alphas = (const float*)d_in[1];   // [B,T]   f32
    const int*   tlen   = (const int*)d_in[2];     // [B]     i32
    float* out = (float*)d_out;                    // [B,L,H] f32

    float* alphasT = (float*)d_ws;                 // TP*BB floats = 256 KB
    int2*  rec     = (int2*)(alphasT + TP * BB);
    int*   nfires  = (int*)(rec + BB * LL);
    float* scale_g = (float*)(nfires + BB);

    cif_scale_kernel<<<BB, 256, 0, stream>>>(alphas, tlen, scale_g, alphasT);
    cif_scan_kernel<<<1, 256, 0, stream>>>(alphasT, rec, nfires);
    cif_gather_kernel<<<dim3(LL, BB), 128, 0, stream>>>(hidden, alphas, scale_g,
                                                        rec, nfires, out);
}